// Round 1
// baseline (5770.145 us; speedup 1.0000x reference)
//
#include <hip/hip_runtime.h>
#include <math.h>

#define B 4096
#define C 8192
#define T 100
#define TCHUNK 10
#define THREADS 512
#define HB (B / 2)          // 2048 row pairs
#define NWAVE (THREADS / 64)

// ws layout (floats): [0..T): per-t sum over rows of (lse - zy - eps_y*sig)
//                     [T]   : sum over rows of undistorted per-sample loss
//                     [T+1] : sum over rows of expm1(logit_var)

__global__ void zero_ws_kernel(float* __restrict__ ws) {
    int i = threadIdx.x;
    if (i < T + 2) ws[i] = 0.0f;
}

__device__ __forceinline__ unsigned rotl32(unsigned x, int r) {
    return (x << r) | (x >> (32 - r));
}

// Threefry-2x32, 20 rounds (full strength). Counter (x0,x1), fixed key.
__device__ __forceinline__ void threefry2x32(unsigned x0, unsigned x1,
                                             unsigned& o0, unsigned& o1) {
    const unsigned ks0 = 0x243F6A88u, ks1 = 0x85A308D3u;
    const unsigned ks2 = ks0 ^ ks1 ^ 0x1BD11BDAu;
    x0 += ks0; x1 += ks1;
#define TF_R(r) { x0 += x1; x1 = rotl32(x1, r); x1 ^= x0; }
    TF_R(13) TF_R(15) TF_R(26) TF_R(6)
    x0 += ks1; x1 += ks2 + 1u;
    TF_R(17) TF_R(29) TF_R(16) TF_R(24)
    x0 += ks2; x1 += ks0 + 2u;
    TF_R(13) TF_R(15) TF_R(26) TF_R(6)
    x0 += ks0; x1 += ks1 + 3u;
    TF_R(17) TF_R(29) TF_R(16) TF_R(24)
    x0 += ks1; x1 += ks2 + 4u;
    TF_R(13) TF_R(15) TF_R(26) TF_R(6)
    x0 += ks2; x1 += ks0 + 5u;
#undef TF_R
    o0 = x0; o1 = x1;
}

// Undistorted per-row CE + variance_depressor partials.
__global__ __launch_bounds__(256) void rowstats_kernel(
    const float* __restrict__ logit, const float* __restrict__ logit_var,
    const int* __restrict__ truth, float* __restrict__ ws) {
    __shared__ float red[4];
    const int b = blockIdx.x;
    const int tid = threadIdx.x;
    const float* row = logit + (size_t)b * C;
    float s = 0.0f;
    for (int c = tid; c < C; c += 256) s += __expf(row[c]);
#pragma unroll
    for (int off = 32; off; off >>= 1) s += __shfl_down(s, off, 64);
    if ((tid & 63) == 0) red[tid >> 6] = s;
    __syncthreads();
    if (tid == 0) {
        float tot = red[0] + red[1] + red[2] + red[3];
        float loss = logf(tot) - row[truth[b]];
        atomicAdd(&ws[T], loss);
        atomicAdd(&ws[T + 1], expm1f(logit_var[b]));
    }
}

// Monte-Carlo kernel: block = (row pair b, b+HB) x (chunk of TCHUNK t's).
__global__ __launch_bounds__(THREADS) void mc_kernel(
    const float* __restrict__ logit, const float* __restrict__ logit_var,
    const int* __restrict__ truth, float* __restrict__ ws) {
    __shared__ __align__(16) float zrow0[C];
    __shared__ __align__(16) float zrow1[C];
    __shared__ float4 red4[NWAVE];

    const int tid = threadIdx.x;
    const int b0 = blockIdx.x;
    const int b1 = b0 + HB;
    const float* r0 = logit + (size_t)b0 * C;
    const float* r1 = logit + (size_t)b1 * C;

    // stage both rows into LDS (vectorized, coalesced)
    {
        const float4* s0 = (const float4*)r0;
        const float4* s1 = (const float4*)r1;
        float4* d0 = (float4*)zrow0;
        float4* d1 = (float4*)zrow1;
#pragma unroll
        for (int i = 0; i < C / 4 / THREADS; ++i) {
            d0[i * THREADS + tid] = s0[i * THREADS + tid];
            d1[i * THREADS + tid] = s1[i * THREADS + tid];
        }
    }
    const int y0 = truth[b0], y1 = truth[b1];
    const float sig0 = sqrtf(logit_var[b0]);
    const float sig1 = sqrtf(logit_var[b1]);
    const float zy0 = r0[y0], zy1 = r1[y1];
    __syncthreads();

    const unsigned jbase = ((unsigned)b0 << 13);  // b0 * C

    for (int tt = 0; tt < TCHUNK; ++tt) {
        const unsigned t = blockIdx.y * TCHUNK + (unsigned)tt;
        float se0 = 0.0f, se1 = 0.0f, ey0 = 0.0f, ey1 = 0.0f;
#pragma unroll 4
        for (int k = 0; k < C / THREADS; ++k) {   // 16 iterations
            const int c = k * THREADS + tid;
            unsigned o0, o1;
            threefry2x32(t, jbase + (unsigned)c, o0, o1);
            // Box-Muller: two exact standard normals from two uniforms
            const float u1 = (float)(o0 >> 8) * 0x1p-24f + 0x1p-25f;  // (0,1)
            const float u2 = (float)(o1 >> 8) * 0x1p-24f;             // [0,1)
            const float rr = sqrtf(-2.0f * __logf(u1));
            const float ang = 6.28318530718f * u2;
            const float e0 = rr * __cosf(ang);
            const float e1 = rr * __sinf(ang);
            const float p0 = e0 * sig0;
            const float p1 = e1 * sig1;
            se0 += __expf(zrow0[c] + p0);
            se1 += __expf(zrow1[c] + p1);
            ey0 += (c == y0) ? p0 : 0.0f;
            ey1 += (c == y1) ? p1 : 0.0f;
        }
        float4 v = make_float4(se0, se1, ey0, ey1);
#pragma unroll
        for (int off = 32; off; off >>= 1) {
            v.x += __shfl_down(v.x, off, 64);
            v.y += __shfl_down(v.y, off, 64);
            v.z += __shfl_down(v.z, off, 64);
            v.w += __shfl_down(v.w, off, 64);
        }
        __syncthreads();   // protect red4 from previous iteration's consumer
        if ((tid & 63) == 0) red4[tid >> 6] = v;
        __syncthreads();
        if (tid == 0) {
            float a0 = 0.f, a1 = 0.f, a2 = 0.f, a3 = 0.f;
#pragma unroll
            for (int w = 0; w < NWAVE; ++w) {
                a0 += red4[w].x; a1 += red4[w].y;
                a2 += red4[w].z; a3 += red4[w].w;
            }
            const float contrib = (logf(a0) - zy0 - a2) + (logf(a1) - zy1 - a3);
            atomicAdd(&ws[t], contrib);
        }
    }
}

__global__ __launch_bounds__(64) void finalize_kernel(
    const float* __restrict__ ws, float* __restrict__ out) {
    const int lane = threadIdx.x;
    const float invB = 1.0f / (float)B;
    const float u = ws[T] * invB;   // undistorted_loss
    float g = 0.0f, v = 0.0f;
    for (int t = lane; t < T; t += 64) {
        const float dist = ws[t] * invB;
        g += dist;
        const float df = u - dist;
        v -= (df > 0.0f) ? df : expm1f(df);   // -elu(diff)
    }
#pragma unroll
    for (int off = 32; off; off >>= 1) {
        g += __shfl_down(g, off, 64);
        v += __shfl_down(v, off, 64);
    }
    if (lane == 0) {
        out[0] = g / (float)T;        // gce_loss
        out[1] = v / (float)T;        // variance_loss
        out[2] = u;                   // undistorted_loss
        out[3] = ws[T + 1] * invB;    // variance_depressor
    }
}

extern "C" void kernel_launch(void* const* d_in, const int* in_sizes, int n_in,
                              void* d_out, int out_size, void* d_ws, size_t ws_size,
                              hipStream_t stream) {
    const float* logit_var = (const float*)d_in[0];
    const float* logit     = (const float*)d_in[1];
    const int*   truth     = (const int*)d_in[2];
    float* out = (float*)d_out;
    float* ws  = (float*)d_ws;

    hipLaunchKernelGGL(zero_ws_kernel, dim3(1), dim3(128), 0, stream, ws);
    hipLaunchKernelGGL(rowstats_kernel, dim3(B), dim3(256), 0, stream,
                       logit, logit_var, truth, ws);
    hipLaunchKernelGGL(mc_kernel, dim3(HB, T / TCHUNK), dim3(THREADS), 0, stream,
                       logit, logit_var, truth, ws);
    hipLaunchKernelGGL(finalize_kernel, dim3(1), dim3(64), 0, stream, ws, out);
}

// Round 2
// 2620.108 us; speedup vs baseline: 2.2023x; 2.2023x over previous
//
#include <hip/hip_runtime.h>
#include <math.h>

#define B 4096
#define C 8192
#define T 100
#define TCHUNK 10
#define THREADS 512
#define NWAVE (THREADS / 64)
#define LOG2E 1.44269504f
#define LN2 0.69314718f
#define SALT 0x9E3779B9u

// ws layout (floats):
//  [0..T)  : per-t  sum_b ( lse(b,t) - sigma_b * eps_y(b,t) )
//  [T]     : sum_b undistorted per-sample loss
//  [T+1]   : sum_b expm1(logit_var_b)
//  [T+2]   : sum_b z_y(b)

__global__ void zero_ws_kernel(float* __restrict__ ws) {
    int i = threadIdx.x;
    if (i < T + 3) ws[i] = 0.0f;
}

// pcg4d hash (Jarzynski & Olano) — 4x32-bit out for 4x32-bit counter in.
__device__ __forceinline__ uint4 pcg4d(unsigned a, unsigned b, unsigned c, unsigned d) {
    a = a * 1664525u + 1013904223u;
    b = b * 1664525u + 1013904223u;
    c = c * 1664525u + 1013904223u;
    d = d * 1664525u + 1013904223u;
    a += b * d; b += c * a; c += a * b; d += b * c;
    a ^= a >> 16; b ^= b >> 16; c ^= c >> 16; d ^= d >> 16;
    a += b * d; b += c * a; c += a * b; d += b * c;
    return make_uint4(a, b, c, d);
}

// Box-Muller pair from one 32-bit word (two 16-bit uniforms), pre-scaled by `scale`.
// e0 = scale * r * cos(2*pi*u2), e1 = scale * r * sin(2*pi*u2), r = sqrt(-2 ln u1).
__device__ __forceinline__ void bm_pair(unsigned w, float scale, float& e0, float& e1) {
    const float l = __builtin_amdgcn_logf((float)((w & 0xffffu) | 1u)); // log2(v), v in [1,65535]
    // -2 ln(v * 2^-16) = (16 - log2 v) * 2ln2 = fma(l, -2ln2, 32ln2)
    const float rr = __builtin_amdgcn_sqrtf(fmaf(l, -1.38629436f, 22.1807097f));
    const float rs = rr * scale;
    const float u2 = (float)(w >> 16) * 0x1p-16f;      // [0,1) revolutions
    e0 = rs * __builtin_amdgcn_cosf(u2);               // v_cos: input in revolutions
    e1 = rs * __builtin_amdgcn_sinf(u2);
}

// Undistorted per-row CE + variance_depressor + sum of z_y.
__global__ __launch_bounds__(256) void rowstats_kernel(
    const float* __restrict__ logit, const float* __restrict__ logit_var,
    const int* __restrict__ truth, float* __restrict__ ws) {
    __shared__ float red[4];
    const int b = blockIdx.x;
    const int tid = threadIdx.x;
    const float* row = logit + (size_t)b * C;
    float s = 0.0f;
    for (int c = tid; c < C; c += 256) s += __expf(row[c]);
#pragma unroll
    for (int off = 32; off; off >>= 1) s += __shfl_down(s, off, 64);
    if ((tid & 63) == 0) red[tid >> 6] = s;
    __syncthreads();
    if (tid == 0) {
        const float zy = row[truth[b]];
        const float tot = red[0] + red[1] + red[2] + red[3];
        atomicAdd(&ws[T], logf(tot) - zy);
        atomicAdd(&ws[T + 1], expm1f(logit_var[b]));
        atomicAdd(&ws[T + 2], zy);
    }
}

// eps at the true label: one hash eval per (b,t); subtract sigma*eps_y into ws[t].
__global__ __launch_bounds__(256) void epsy_kernel(
    const float* __restrict__ logit_var, const int* __restrict__ truth,
    float* __restrict__ ws) {
    __shared__ float red[4];
    const unsigned t = blockIdx.x;
    const int tid = threadIdx.x;
    float acc = 0.0f;
    for (int b = tid; b < B; b += 256) {
        const unsigned y = (unsigned)truth[b];
        const unsigned g = (y & 4095u) >> 2;                      // group within half
        const uint4 h = pcg4d((unsigned)b, g, t, SALT);
        const unsigned wsel = ((y >> 12) & 1u) * 2u + ((y >> 1) & 1u);
        const unsigned w = wsel == 0u ? h.x : wsel == 1u ? h.y : wsel == 2u ? h.z : h.w;
        float e0, e1;
        bm_pair(w, __builtin_amdgcn_sqrtf(logit_var[b]), e0, e1);
        acc += (y & 1u) ? e1 : e0;
    }
#pragma unroll
    for (int off = 32; off; off >>= 1) acc += __shfl_down(acc, off, 64);
    if ((tid & 63) == 0) red[tid >> 6] = acc;
    __syncthreads();
    if (tid == 0) atomicAdd(&ws[t], -(red[0] + red[1] + red[2] + red[3]));
}

// Monte-Carlo LSE kernel: block = (row b) x (chunk of TCHUNK t's).
// Mapping: lane group g in [0,1024) covers quads (g, g+1024):
//   h.x -> cols 4g,4g+1 ; h.y -> 4g+2,4g+3 ; h.z -> 4g+4096,+1 ; h.w -> 4g+4098,+1
__global__ __launch_bounds__(THREADS) void mc_kernel(
    const float* __restrict__ logit, const float* __restrict__ logit_var,
    float* __restrict__ ws) {
    __shared__ __align__(16) float zs[C];   // z * log2e
    __shared__ float red[NWAVE];

    const int tid = threadIdx.x;
    const unsigned b = blockIdx.x;
    const float4* src = (const float4*)(logit + (size_t)b * C);
    float4* dst = (float4*)zs;
#pragma unroll
    for (int i = 0; i < C / 4 / THREADS; ++i) {
        float4 v = src[i * THREADS + tid];
        v.x *= LOG2E; v.y *= LOG2E; v.z *= LOG2E; v.w *= LOG2E;
        dst[i * THREADS + tid] = v;
    }
    const float sl2 = __builtin_amdgcn_sqrtf(logit_var[b]) * LOG2E;
    __syncthreads();

    const float4* z4 = (const float4*)zs;
    for (int tt = 0; tt < TCHUNK; ++tt) {
        const unsigned t = blockIdx.y * TCHUNK + (unsigned)tt;
        float sa = 0.0f, sb = 0.0f;
#pragma unroll
        for (int k = 0; k < 2; ++k) {
            const unsigned g = (unsigned)(k * THREADS + tid);
            const uint4 h = pcg4d(b, g, t, SALT);
            const float4 zA = z4[g];
            const float4 zB = z4[g + 1024];
            float e0, e1;
            bm_pair(h.x, sl2, e0, e1);
            sa += __builtin_amdgcn_exp2f(zA.x + e0);
            sb += __builtin_amdgcn_exp2f(zA.y + e1);
            bm_pair(h.y, sl2, e0, e1);
            sa += __builtin_amdgcn_exp2f(zA.z + e0);
            sb += __builtin_amdgcn_exp2f(zA.w + e1);
            bm_pair(h.z, sl2, e0, e1);
            sa += __builtin_amdgcn_exp2f(zB.x + e0);
            sb += __builtin_amdgcn_exp2f(zB.y + e1);
            bm_pair(h.w, sl2, e0, e1);
            sa += __builtin_amdgcn_exp2f(zB.z + e0);
            sb += __builtin_amdgcn_exp2f(zB.w + e1);
        }
        float se = sa + sb;
#pragma unroll
        for (int off = 32; off; off >>= 1) se += __shfl_down(se, off, 64);
        __syncthreads();
        if ((tid & 63) == 0) red[tid >> 6] = se;
        __syncthreads();
        if (tid == 0) {
            float a = 0.0f;
#pragma unroll
            for (int w = 0; w < NWAVE; ++w) a += red[w];
            atomicAdd(&ws[t], __builtin_amdgcn_logf(a) * LN2);  // ln = log2 * ln2
        }
    }
}

__global__ __launch_bounds__(64) void finalize_kernel(
    const float* __restrict__ ws, float* __restrict__ out) {
    const int lane = threadIdx.x;
    const float invB = 1.0f / (float)B;
    const float u = ws[T] * invB;     // undistorted_loss
    const float szy = ws[T + 2];      // sum of z_y over rows
    float g = 0.0f, v = 0.0f;
    for (int t = lane; t < T; t += 64) {
        const float dist = (ws[t] - szy) * invB;
        g += dist;
        const float df = u - dist;
        v -= (df > 0.0f) ? df : expm1f(df);   // -elu(diff)
    }
#pragma unroll
    for (int off = 32; off; off >>= 1) {
        g += __shfl_down(g, off, 64);
        v += __shfl_down(v, off, 64);
    }
    if (lane == 0) {
        out[0] = g / (float)T;        // gce_loss
        out[1] = v / (float)T;        // variance_loss
        out[2] = u;                   // undistorted_loss
        out[3] = ws[T + 1] * invB;    // variance_depressor
    }
}

extern "C" void kernel_launch(void* const* d_in, const int* in_sizes, int n_in,
                              void* d_out, int out_size, void* d_ws, size_t ws_size,
                              hipStream_t stream) {
    const float* logit_var = (const float*)d_in[0];
    const float* logit     = (const float*)d_in[1];
    const int*   truth     = (const int*)d_in[2];
    float* out = (float*)d_out;
    float* ws  = (float*)d_ws;

    hipLaunchKernelGGL(zero_ws_kernel, dim3(1), dim3(128), 0, stream, ws);
    hipLaunchKernelGGL(rowstats_kernel, dim3(B), dim3(256), 0, stream,
                       logit, logit_var, truth, ws);
    hipLaunchKernelGGL(epsy_kernel, dim3(T), dim3(256), 0, stream,
                       logit_var, truth, ws);
    hipLaunchKernelGGL(mc_kernel, dim3(B, T / TCHUNK), dim3(THREADS), 0, stream,
                       logit, logit_var, ws);
    hipLaunchKernelGGL(finalize_kernel, dim3(1), dim3(64), 0, stream, ws, out);
}

// Round 3
// 1266.645 us; speedup vs baseline: 4.5555x; 2.0685x over previous
//
#include <hip/hip_runtime.h>
#include <math.h>

#define B 4096
#define C 8192
#define T 100
#define TCHUNK 10
#define THREADS 512
#define NWAVE (THREADS / 64)
#define SLOTS 16
#define TS (T * SLOTS)
#define LOG2E 1.44269504f
#define LN2 0.69314718f
#define SALT 0x9E3779B9u

// ws layout (floats):
//  [0 .. TS)  : slotted per-t sums of ( lse(b,t) - sigma_b*eps_y(b,t) ), slot = b & 15
//  [TS]       : sum_b undistorted per-sample loss
//  [TS+1]     : sum_b expm1(logit_var_b)
//  [TS+2]     : sum_b z_y(b)

__global__ void zero_ws_kernel(float* __restrict__ ws) {
    const int i = blockIdx.x * 256 + threadIdx.x;
    if (i < TS + 3) ws[i] = 0.0f;
}

// pcg4d hash (Jarzynski & Olano) — 4x32-bit out for 4x32-bit counter in.
__device__ __forceinline__ uint4 pcg4d(unsigned a, unsigned b, unsigned c, unsigned d) {
    a = a * 1664525u + 1013904223u;
    b = b * 1664525u + 1013904223u;
    c = c * 1664525u + 1013904223u;
    d = d * 1664525u + 1013904223u;
    a += b * d; b += c * a; c += a * b; d += b * c;
    a ^= a >> 16; b ^= b >> 16; c ^= c >> 16; d ^= d >> 16;
    a += b * d; b += c * a; c += a * b; d += b * c;
    return make_uint4(a, b, c, d);
}

// Box-Muller pair in natural units (for epsy): e0/e1 = scale * r * cos/sin.
__device__ __forceinline__ void bm_pair(unsigned w, float scale, float& e0, float& e1) {
    const float l = __builtin_amdgcn_logf((float)((w & 0xffffu) | 1u)); // log2(v)
    const float rr = __builtin_amdgcn_sqrtf(fmaf(l, -1.38629436f, 22.1807097f));
    const float rs = rr * scale;
    const float u2 = (float)(w >> 16) * 0x1p-16f;      // [0,1) revolutions
    e0 = rs * __builtin_amdgcn_cosf(u2);
    e1 = rs * __builtin_amdgcn_sinf(u2);
}

// One 4-word group: 8 exp2 terms, fully batched for ILP. z* are pre-scaled by log2e,
// sl2 = sigma * log2e.
__device__ __forceinline__ float mc_group(uint4 h, float4 zA, float4 zB, float sl2) {
    unsigned w[4] = {h.x, h.y, h.z, h.w};
    float rs[4], cv[4], sv[4];
#pragma unroll
    for (int i = 0; i < 4; ++i) {
        const float l = __builtin_amdgcn_logf((float)((w[i] & 0xffffu) | 1u));
        rs[i] = __builtin_amdgcn_sqrtf(fmaf(l, -1.38629436f, 22.1807097f)) * sl2;
        const float u2 = (float)(w[i] >> 16) * 0x1p-16f;
        cv[i] = __builtin_amdgcn_cosf(u2);
        sv[i] = __builtin_amdgcn_sinf(u2);
    }
    const float p0 = __builtin_amdgcn_exp2f(fmaf(cv[0], rs[0], zA.x))
                   + __builtin_amdgcn_exp2f(fmaf(sv[0], rs[0], zA.y));
    const float p1 = __builtin_amdgcn_exp2f(fmaf(cv[1], rs[1], zA.z))
                   + __builtin_amdgcn_exp2f(fmaf(sv[1], rs[1], zA.w));
    const float p2 = __builtin_amdgcn_exp2f(fmaf(cv[2], rs[2], zB.x))
                   + __builtin_amdgcn_exp2f(fmaf(sv[2], rs[2], zB.y));
    const float p3 = __builtin_amdgcn_exp2f(fmaf(cv[3], rs[3], zB.z))
                   + __builtin_amdgcn_exp2f(fmaf(sv[3], rs[3], zB.w));
    return (p0 + p1) + (p2 + p3);
}

// Undistorted per-row CE + variance_depressor + sum of z_y.
__global__ __launch_bounds__(256) void rowstats_kernel(
    const float* __restrict__ logit, const float* __restrict__ logit_var,
    const int* __restrict__ truth, float* __restrict__ ws) {
    __shared__ float red[4];
    const int b = blockIdx.x;
    const int tid = threadIdx.x;
    const float* row = logit + (size_t)b * C;
    float s = 0.0f;
    for (int c = tid; c < C; c += 256) s += __expf(row[c]);
#pragma unroll
    for (int off = 32; off; off >>= 1) s += __shfl_down(s, off, 64);
    if ((tid & 63) == 0) red[tid >> 6] = s;
    __syncthreads();
    if (tid == 0) {
        const float zy = row[truth[b]];
        const float tot = red[0] + red[1] + red[2] + red[3];
        atomicAdd(&ws[TS], logf(tot) - zy);
        atomicAdd(&ws[TS + 1], expm1f(logit_var[b]));
        atomicAdd(&ws[TS + 2], zy);
    }
}

// eps at the true label: one hash eval per (b,t); subtract sigma*eps_y into ws[t] slot 0.
__global__ __launch_bounds__(256) void epsy_kernel(
    const float* __restrict__ logit_var, const int* __restrict__ truth,
    float* __restrict__ ws) {
    __shared__ float red[4];
    const unsigned t = blockIdx.x;
    const int tid = threadIdx.x;
    float acc = 0.0f;
    for (int b = tid; b < B; b += 256) {
        const unsigned y = (unsigned)truth[b];
        const unsigned g = (y & 4095u) >> 2;
        const uint4 h = pcg4d((unsigned)b, g, t, SALT);
        const unsigned wsel = ((y >> 12) & 1u) * 2u + ((y >> 1) & 1u);
        const unsigned w = wsel == 0u ? h.x : wsel == 1u ? h.y : wsel == 2u ? h.z : h.w;
        float e0, e1;
        bm_pair(w, __builtin_amdgcn_sqrtf(logit_var[b]), e0, e1);
        acc += (y & 1u) ? e1 : e0;
    }
#pragma unroll
    for (int off = 32; off; off >>= 1) acc += __shfl_down(acc, off, 64);
    if ((tid & 63) == 0) red[tid >> 6] = acc;
    __syncthreads();
    if (tid == 0) atomicAdd(&ws[t * SLOTS], -(red[0] + red[1] + red[2] + red[3]));
}

// Monte-Carlo LSE kernel: block = (row b) x (chunk of TCHUNK t's).
// Column mapping per lane-group g = k*512+tid (k in {0,1}):
//   h.x -> cols 4g,4g+1 ; h.y -> 4g+2,4g+3 ; h.z -> 4g+4096,+1 ; h.w -> 4g+4098,+1
__global__ __launch_bounds__(THREADS) void mc_kernel(
    const float* __restrict__ logit, const float* __restrict__ logit_var,
    float* __restrict__ ws) {
    __shared__ __align__(16) float zs[C];      // z * log2e
    __shared__ float red[NWAVE][TCHUNK];

    const int tid = threadIdx.x;
    const unsigned b = blockIdx.x;
    const float4* src = (const float4*)(logit + (size_t)b * C);
    float4* dst = (float4*)zs;
#pragma unroll
    for (int i = 0; i < C / 4 / THREADS; ++i) {
        float4 v = src[i * THREADS + tid];
        v.x *= LOG2E; v.y *= LOG2E; v.z *= LOG2E; v.w *= LOG2E;
        dst[i * THREADS + tid] = v;
    }
    const float sl2 = __builtin_amdgcn_sqrtf(logit_var[b]) * LOG2E;
    __syncthreads();

    const float4* z4 = (const float4*)zs;
    // loop-invariant: this thread's 16 logits live in registers for the whole t-loop
    const float4 zA0 = z4[tid];
    const float4 zB0 = z4[tid + 1024];
    const float4 zA1 = z4[tid + 512];
    const float4 zB1 = z4[tid + 1536];

    const unsigned tbase = blockIdx.y * TCHUNK;
    const int wid = tid >> 6;
    const unsigned slot = b & (SLOTS - 1);

    for (int tt = 0; tt < TCHUNK; ++tt) {
        const unsigned t = tbase + (unsigned)tt;
        const uint4 h0 = pcg4d(b, (unsigned)tid, t, SALT);
        const uint4 h1 = pcg4d(b, (unsigned)tid + 512u, t, SALT);
        float s = mc_group(h0, zA0, zB0, sl2) + mc_group(h1, zA1, zB1, sl2);
#pragma unroll
        for (int off = 32; off; off >>= 1) s += __shfl_down(s, off, 64);
        if ((tid & 63) == 0) red[wid][tt] = s;
    }
    __syncthreads();
    if (tid < TCHUNK) {
        float a = 0.0f;
#pragma unroll
        for (int w = 0; w < NWAVE; ++w) a += red[w][tid];
        atomicAdd(&ws[(tbase + (unsigned)tid) * SLOTS + slot],
                  __builtin_amdgcn_logf(a) * LN2);   // ln = log2 * ln2
    }
}

__global__ __launch_bounds__(64) void finalize_kernel(
    const float* __restrict__ ws, float* __restrict__ out) {
    const int lane = threadIdx.x;
    const float invB = 1.0f / (float)B;
    const float u = ws[TS] * invB;     // undistorted_loss
    const float szy = ws[TS + 2];      // sum of z_y over rows
    float g = 0.0f, v = 0.0f;
    for (int t = lane; t < T; t += 64) {
        float sumt = 0.0f;
#pragma unroll
        for (int s = 0; s < SLOTS; ++s) sumt += ws[t * SLOTS + s];
        const float dist = (sumt - szy) * invB;
        g += dist;
        const float df = u - dist;
        v -= (df > 0.0f) ? df : expm1f(df);   // -elu(diff)
    }
#pragma unroll
    for (int off = 32; off; off >>= 1) {
        g += __shfl_down(g, off, 64);
        v += __shfl_down(v, off, 64);
    }
    if (lane == 0) {
        out[0] = g / (float)T;        // gce_loss
        out[1] = v / (float)T;        // variance_loss
        out[2] = u;                   // undistorted_loss
        out[3] = ws[TS + 1] * invB;   // variance_depressor
    }
}

extern "C" void kernel_launch(void* const* d_in, const int* in_sizes, int n_in,
                              void* d_out, int out_size, void* d_ws, size_t ws_size,
                              hipStream_t stream) {
    const float* logit_var = (const float*)d_in[0];
    const float* logit     = (const float*)d_in[1];
    const int*   truth     = (const int*)d_in[2];
    float* out = (float*)d_out;
    float* ws  = (float*)d_ws;

    hipLaunchKernelGGL(zero_ws_kernel, dim3((TS + 3 + 255) / 256), dim3(256), 0, stream, ws);
    hipLaunchKernelGGL(rowstats_kernel, dim3(B), dim3(256), 0, stream,
                       logit, logit_var, truth, ws);
    hipLaunchKernelGGL(epsy_kernel, dim3(T), dim3(256), 0, stream,
                       logit_var, truth, ws);
    hipLaunchKernelGGL(mc_kernel, dim3(B, T / TCHUNK), dim3(THREADS), 0, stream,
                       logit, logit_var, ws);
    hipLaunchKernelGGL(finalize_kernel, dim3(1), dim3(64), 0, stream, ws, out);
}

// Round 4
// 933.875 us; speedup vs baseline: 6.1787x; 1.3563x over previous
//
#include <hip/hip_runtime.h>
#include <math.h>

#define B 4096
#define C 8192
#define T 100
#define TCHUNK 10
#define NPAIR (TCHUNK / 2)
#define THREADS 512
#define NWAVE (THREADS / 64)
#define SLOTS 16
#define TS (T * SLOTS)
#define LOG2E 1.44269504f
#define LN2 0.69314718f
#define SALT 0x9E3779B9u

typedef float v2f __attribute__((ext_vector_type(2)));

// ws layout (floats):
//  [0 .. TS)  : slotted per-t sums of ( lse(b,t) - sigma_b*eps_y(b,t) ), slot = b & 15
//  [TS]       : sum_b undistorted per-sample loss
//  [TS+1]     : sum_b expm1(logit_var_b)
//  [TS+2]     : sum_b z_y(b)

__global__ void zero_ws_kernel(float* __restrict__ ws) {
    const int i = blockIdx.x * 256 + threadIdx.x;
    if (i < TS + 3) ws[i] = 0.0f;
}

// pcg4d hash (Jarzynski & Olano) — 4x32-bit out for 4x32-bit counter in.
__device__ __forceinline__ uint4 pcg4d(unsigned a, unsigned b, unsigned c, unsigned d) {
    a = a * 1664525u + 1013904223u;
    b = b * 1664525u + 1013904223u;
    c = c * 1664525u + 1013904223u;
    d = d * 1664525u + 1013904223u;
    a += b * d; b += c * a; c += a * b; d += b * c;
    a ^= a >> 16; b ^= b >> 16; c ^= c >> 16; d ^= d >> 16;
    a += b * d; b += c * a; c += a * b; d += b * c;
    return make_uint4(a, b, c, d);
}

// Box-Muller pair in natural units (for epsy): e0/e1 = scale * r * cos/sin(2*pi*u2).
__device__ __forceinline__ void bm_pair(unsigned w, float scale, float& e0, float& e1) {
    const float l = __builtin_amdgcn_logf((float)((w & 0xffffu) | 1u)); // log2(v)
    const float rr = __builtin_amdgcn_sqrtf(fmaf(l, -1.38629436f, 22.1807097f));
    const float rs = rr * scale;
    const float u2 = (float)(w >> 16) * 0x1p-16f;      // [0,1) revolutions
    e0 = rs * __builtin_amdgcn_cosf(u2);
    e1 = rs * __builtin_amdgcn_sinf(u2);
}

// Antithetic group: 4 words -> 8 elements, accumulates
//   acc.x += sum exp2(z + p), acc.y += sum exp2(z - p).
// z* pre-scaled by log2e; sl2 = sigma * log2e.
__device__ __forceinline__ void mc_group_anti(uint4 h, float4 zA, float4 zB,
                                              float sl2, v2f& acc) {
    unsigned w[4] = {h.x, h.y, h.z, h.w};
    float z0[4] = {zA.x, zA.z, zB.x, zB.z};   // cos-elements
    float z1[4] = {zA.y, zA.w, zB.y, zB.w};   // sin-elements
    float rs[4], cv[4], sv[4];
#pragma unroll
    for (int i = 0; i < 4; ++i) {
        const float l = __builtin_amdgcn_logf((float)((w[i] & 0xffffu) | 1u));
        rs[i] = __builtin_amdgcn_sqrtf(fmaf(l, -1.38629436f, 22.1807097f)) * sl2;
        const float u2 = (float)(w[i] >> 16) * 0x1p-16f;
        cv[i] = __builtin_amdgcn_cosf(u2);
        sv[i] = __builtin_amdgcn_sinf(u2);
    }
#pragma unroll
    for (int i = 0; i < 4; ++i) {
        v2f rr; rr.x = rs[i]; rr.y = -rs[i];
        v2f c2; c2.x = cv[i]; c2.y = cv[i];
        v2f zz; zz.x = z0[i]; zz.y = z0[i];
        const v2f a0 = __builtin_elementwise_fma(c2, rr, zz);
        v2f s2; s2.x = sv[i]; s2.y = sv[i];
        v2f zw; zw.x = z1[i]; zw.y = z1[i];
        const v2f a1 = __builtin_elementwise_fma(s2, rr, zw);
        v2f e0; e0.x = __builtin_amdgcn_exp2f(a0.x); e0.y = __builtin_amdgcn_exp2f(a0.y);
        v2f e1; e1.x = __builtin_amdgcn_exp2f(a1.x); e1.y = __builtin_amdgcn_exp2f(a1.y);
        acc += e0 + e1;
    }
}

// Undistorted per-row CE + variance_depressor + sum of z_y.
__global__ __launch_bounds__(256) void rowstats_kernel(
    const float* __restrict__ logit, const float* __restrict__ logit_var,
    const int* __restrict__ truth, float* __restrict__ ws) {
    __shared__ float red[4];
    const int b = blockIdx.x;
    const int tid = threadIdx.x;
    const float* row = logit + (size_t)b * C;
    float s = 0.0f;
    for (int c = tid; c < C; c += 256) s += __expf(row[c]);
#pragma unroll
    for (int off = 32; off; off >>= 1) s += __shfl_down(s, off, 64);
    if ((tid & 63) == 0) red[tid >> 6] = s;
    __syncthreads();
    if (tid == 0) {
        const float zy = row[truth[b]];
        const float tot = red[0] + red[1] + red[2] + red[3];
        atomicAdd(&ws[TS], logf(tot) - zy);
        atomicAdd(&ws[TS + 1], expm1f(logit_var[b]));
        atomicAdd(&ws[TS + 2], zy);
    }
}

// eps at the true label per antithetic pair k: subtract sigma*eps_y at t=2k,
// add it at t=2k+1 (eps flips sign).
__global__ __launch_bounds__(256) void epsy_kernel(
    const float* __restrict__ logit_var, const int* __restrict__ truth,
    float* __restrict__ ws) {
    __shared__ float red[4];
    const unsigned k = blockIdx.x;       // pair index in [0, T/2)
    const int tid = threadIdx.x;
    float acc = 0.0f;
    for (int b = tid; b < B; b += 256) {
        const unsigned y = (unsigned)truth[b];
        const unsigned g = (y & 4095u) >> 2;
        const uint4 h = pcg4d((unsigned)b, g, k, SALT);
        const unsigned wsel = ((y >> 12) & 1u) * 2u + ((y >> 1) & 1u);
        const unsigned w = wsel == 0u ? h.x : wsel == 1u ? h.y : wsel == 2u ? h.z : h.w;
        float e0, e1;
        bm_pair(w, __builtin_amdgcn_sqrtf(logit_var[b]), e0, e1);
        acc += (y & 1u) ? e1 : e0;
    }
#pragma unroll
    for (int off = 32; off; off >>= 1) acc += __shfl_down(acc, off, 64);
    if ((tid & 63) == 0) red[tid >> 6] = acc;
    __syncthreads();
    if (tid == 0) {
        const float v = red[0] + red[1] + red[2] + red[3];
        atomicAdd(&ws[(2u * k) * SLOTS], -v);
        atomicAdd(&ws[(2u * k + 1u) * SLOTS], v);
    }
}

// Monte-Carlo LSE kernel: block = (row b) x (chunk of NPAIR antithetic pairs).
// Column mapping per lane-group g = k*512+tid (k in {0,1}):
//   h.x -> cols 4g,4g+1 ; h.y -> 4g+2,4g+3 ; h.z -> 4g+4096,+1 ; h.w -> 4g+4098,+1
__global__ __launch_bounds__(THREADS) void mc_kernel(
    const float* __restrict__ logit, const float* __restrict__ logit_var,
    float* __restrict__ ws) {
    __shared__ float red[NWAVE][TCHUNK];

    const int tid = threadIdx.x;
    const unsigned b = blockIdx.x;
    const float4* z4 = (const float4*)(logit + (size_t)b * C);

    // this thread's 16 logits, held in registers for the whole chunk (coalesced loads)
    float4 zA0 = z4[tid];
    float4 zA1 = z4[tid + 512];
    float4 zB0 = z4[tid + 1024];
    float4 zB1 = z4[tid + 1536];
#define SC4(v) { v.x *= LOG2E; v.y *= LOG2E; v.z *= LOG2E; v.w *= LOG2E; }
    SC4(zA0) SC4(zA1) SC4(zB0) SC4(zB1)
#undef SC4
    const float sl2 = __builtin_amdgcn_sqrtf(logit_var[b]) * LOG2E;

    const unsigned tbase = blockIdx.y * TCHUNK;
    const unsigned kbase = tbase >> 1;
    const int wid = tid >> 6;
    const unsigned slot = b & (SLOTS - 1);

    for (int pp = 0; pp < NPAIR; ++pp) {
        const unsigned k = kbase + (unsigned)pp;
        const uint4 h0 = pcg4d(b, (unsigned)tid, k, SALT);
        const uint4 h1 = pcg4d(b, (unsigned)tid + 512u, k, SALT);
        v2f acc; acc.x = 0.0f; acc.y = 0.0f;
        mc_group_anti(h0, zA0, zB0, sl2, acc);
        mc_group_anti(h1, zA1, zB1, sl2, acc);
#pragma unroll
        for (int off = 32; off; off >>= 1) {
            acc.x += __shfl_down(acc.x, off, 64);
            acc.y += __shfl_down(acc.y, off, 64);
        }
        if ((tid & 63) == 0) {
            red[wid][2 * pp] = acc.x;       // t = tbase + 2pp   (+eps)
            red[wid][2 * pp + 1] = acc.y;   // t = tbase + 2pp+1 (-eps)
        }
    }
    __syncthreads();
    if (tid < TCHUNK) {
        float a = 0.0f;
#pragma unroll
        for (int w = 0; w < NWAVE; ++w) a += red[w][tid];
        atomicAdd(&ws[(tbase + (unsigned)tid) * SLOTS + slot],
                  __builtin_amdgcn_logf(a) * LN2);   // ln = log2 * ln2
    }
}

__global__ __launch_bounds__(64) void finalize_kernel(
    const float* __restrict__ ws, float* __restrict__ out) {
    const int lane = threadIdx.x;
    const float invB = 1.0f / (float)B;
    const float u = ws[TS] * invB;     // undistorted_loss
    const float szy = ws[TS + 2];      // sum of z_y over rows
    float g = 0.0f, v = 0.0f;
    for (int t = lane; t < T; t += 64) {
        float sumt = 0.0f;
#pragma unroll
        for (int s = 0; s < SLOTS; ++s) sumt += ws[t * SLOTS + s];
        const float dist = (sumt - szy) * invB;
        g += dist;
        const float df = u - dist;
        v -= (df > 0.0f) ? df : expm1f(df);   // -elu(diff)
    }
#pragma unroll
    for (int off = 32; off; off >>= 1) {
        g += __shfl_down(g, off, 64);
        v += __shfl_down(v, off, 64);
    }
    if (lane == 0) {
        out[0] = g / (float)T;        // gce_loss
        out[1] = v / (float)T;        // variance_loss
        out[2] = u;                   // undistorted_loss
        out[3] = ws[TS + 1] * invB;   // variance_depressor
    }
}

extern "C" void kernel_launch(void* const* d_in, const int* in_sizes, int n_in,
                              void* d_out, int out_size, void* d_ws, size_t ws_size,
                              hipStream_t stream) {
    const float* logit_var = (const float*)d_in[0];
    const float* logit     = (const float*)d_in[1];
    const int*   truth     = (const int*)d_in[2];
    float* out = (float*)d_out;
    float* ws  = (float*)d_ws;

    hipLaunchKernelGGL(zero_ws_kernel, dim3((TS + 3 + 255) / 256), dim3(256), 0, stream, ws);
    hipLaunchKernelGGL(rowstats_kernel, dim3(B), dim3(256), 0, stream,
                       logit, logit_var, truth, ws);
    hipLaunchKernelGGL(epsy_kernel, dim3(T / 2), dim3(256), 0, stream,
                       logit_var, truth, ws);
    hipLaunchKernelGGL(mc_kernel, dim3(B, T / TCHUNK), dim3(THREADS), 0, stream,
                       logit, logit_var, ws);
    hipLaunchKernelGGL(finalize_kernel, dim3(1), dim3(64), 0, stream, ws, out);
}

// Round 5
// 758.435 us; speedup vs baseline: 7.6080x; 1.2313x over previous
//
#include <hip/hip_runtime.h>
#include <math.h>

#define B 4096
#define C 8192
#define T 100
#define TCHUNK 20
#define NPAIR (TCHUNK / 2)
#define THREADS 512
#define NWAVE (THREADS / 64)
#define SLOTS 16
#define TS (T * SLOTS)
#define TBL 8192
#define TBLMASK (TBL - 1)
#define TBLOFF (TS + 16)
#define LOG2E 1.44269504f
#define LN2 0.69314718f
#define SALT 0x9E3779B9u

typedef float v2f __attribute__((ext_vector_type(2)));

// ws layout (floats):
//  [0 .. TS)             : slotted per-t sums of ( lse(b,t) - sigma_b*eps_y(b,t) )
//  [TS]                  : sum_b undistorted per-sample loss
//  [TS+1]                : sum_b expm1(logit_var_b)
//  [TS+2]                : sum_b z_y(b)
//  [TBLOFF..TBLOFF+TBL)  : normal quantile table Phi^-1((i+0.5)/TBL)

__global__ void zero_ws_kernel(float* __restrict__ ws) {
    const int i = blockIdx.x * 256 + threadIdx.x;
    if (i < TS + 3) ws[i] = 0.0f;
}

// Acklam inverse normal CDF (double, setup-only).
__global__ void table_kernel(float* __restrict__ gtable) {
    const int i = blockIdx.x * 256 + threadIdx.x;
    if (i >= TBL) return;
    const double p = (i + 0.5) / (double)TBL;
    double x;
    if (p < 0.02425) {
        const double q = sqrt(-2.0 * log(p));
        x = (((((-7.784894002430293e-03*q - 3.223964580411365e-01)*q - 2.400758277161838e+00)*q - 2.549732539343734e+00)*q + 4.374664141464968e+00)*q + 2.938163982698783e+00) /
            ((((7.784695709041462e-03*q + 3.224671290700398e-01)*q + 2.445134137142996e+00)*q + 3.754408661907416e+00)*q + 1.0);
    } else if (p > 0.97575) {
        const double q = sqrt(-2.0 * log(1.0 - p));
        x = -(((((-7.784894002430293e-03*q - 3.223964580411365e-01)*q - 2.400758277161838e+00)*q - 2.549732539343734e+00)*q + 4.374664141464968e+00)*q + 2.938163982698783e+00) /
             ((((7.784695709041462e-03*q + 3.224671290700398e-01)*q + 2.445134137142996e+00)*q + 3.754408661907416e+00)*q + 1.0);
    } else {
        const double q = p - 0.5, r = q * q;
        x = (((((-3.969683028665376e+01*r + 2.209460984245205e+02)*r - 2.759285104469687e+02)*r + 1.383577518672690e+02)*r - 3.066479806614716e+01)*r + 2.506628277459239e+00)*q /
            (((((-5.447609879822406e+01*r + 1.615858368580409e+02)*r - 1.556989798598866e+02)*r + 6.680131188771972e+01)*r - 1.328068155288572e+01)*r + 1.0);
    }
    gtable[i] = (float)x;
}

// pcg4d hash (Jarzynski & Olano).
__device__ __forceinline__ uint4 pcg4d(unsigned a, unsigned b, unsigned c, unsigned d) {
    a = a * 1664525u + 1013904223u;
    b = b * 1664525u + 1013904223u;
    c = c * 1664525u + 1013904223u;
    d = d * 1664525u + 1013904223u;
    a += b * d; b += c * a; c += a * b; d += b * c;
    a ^= a >> 16; b ^= b >> 16; c ^= c >> 16; d ^= d >> 16;
    a += b * d; b += c * a; c += a * b; d += b * c;
    return make_uint4(a, b, c, d);
}

// Antithetic table group: 4 words -> 8 elements; tbl pre-scaled by sigma*log2e.
//   acc.x += sum exp2(z + p), acc.y += sum exp2(z - p)
__device__ __forceinline__ void mc_group_tbl(uint4 h, float4 zA, float4 zB,
                                             const float* __restrict__ tbl, v2f& acc) {
    unsigned w[4] = {h.x, h.y, h.z, h.w};
    float z0[4] = {zA.x, zA.z, zB.x, zB.z};   // even columns
    float z1[4] = {zA.y, zA.w, zB.y, zB.w};   // odd columns
    float pa[4], pb[4];
#pragma unroll
    for (int i = 0; i < 4; ++i) {
        pa[i] = tbl[w[i] & TBLMASK];
        pb[i] = tbl[(w[i] >> 16) & TBLMASK];
    }
#pragma unroll
    for (int i = 0; i < 4; ++i) {
        v2f zz; zz.x = z0[i]; zz.y = z0[i];
        v2f pp; pp.x = pa[i]; pp.y = -pa[i];
        const v2f a0 = zz + pp;
        v2f zw; zw.x = z1[i]; zw.y = z1[i];
        v2f qq; qq.x = pb[i]; qq.y = -pb[i];
        const v2f a1 = zw + qq;
        v2f e0; e0.x = __builtin_amdgcn_exp2f(a0.x); e0.y = __builtin_amdgcn_exp2f(a0.y);
        v2f e1; e1.x = __builtin_amdgcn_exp2f(a1.x); e1.y = __builtin_amdgcn_exp2f(a1.y);
        acc += e0 + e1;
    }
}

// Undistorted per-row CE + variance_depressor + sum of z_y.
__global__ __launch_bounds__(256) void rowstats_kernel(
    const float* __restrict__ logit, const float* __restrict__ logit_var,
    const int* __restrict__ truth, float* __restrict__ ws) {
    __shared__ float red[4];
    const int b = blockIdx.x;
    const int tid = threadIdx.x;
    const float* row = logit + (size_t)b * C;
    float s = 0.0f;
    for (int c = tid; c < C; c += 256) s += __expf(row[c]);
#pragma unroll
    for (int off = 32; off; off >>= 1) s += __shfl_down(s, off, 64);
    if ((tid & 63) == 0) red[tid >> 6] = s;
    __syncthreads();
    if (tid == 0) {
        const float zy = row[truth[b]];
        const float tot = red[0] + red[1] + red[2] + red[3];
        atomicAdd(&ws[TS], logf(tot) - zy);
        atomicAdd(&ws[TS + 1], expm1f(logit_var[b]));
        atomicAdd(&ws[TS + 2], zy);
    }
}

// eps at the true label per antithetic pair k (table from global, unscaled).
__global__ __launch_bounds__(256) void epsy_kernel(
    const float* __restrict__ logit_var, const int* __restrict__ truth,
    const float* __restrict__ gtable, float* __restrict__ ws) {
    __shared__ float red[4];
    const unsigned k = blockIdx.x;       // pair index in [0, T/2)
    const int tid = threadIdx.x;
    float acc = 0.0f;
    for (int b = tid; b < B; b += 256) {
        const unsigned y = (unsigned)truth[b];
        const unsigned g = (y & 4095u) >> 2;
        const uint4 h = pcg4d((unsigned)b, g, k, SALT);
        const unsigned wsel = ((y >> 12) & 1u) * 2u + ((y >> 1) & 1u);
        const unsigned w = wsel == 0u ? h.x : wsel == 1u ? h.y : wsel == 2u ? h.z : h.w;
        const float e = gtable[(y & 1u) ? ((w >> 16) & TBLMASK) : (w & TBLMASK)];
        acc += e * __builtin_amdgcn_sqrtf(logit_var[b]);
    }
#pragma unroll
    for (int off = 32; off; off >>= 1) acc += __shfl_down(acc, off, 64);
    if ((tid & 63) == 0) red[tid >> 6] = acc;
    __syncthreads();
    if (tid == 0) {
        const float v = red[0] + red[1] + red[2] + red[3];
        atomicAdd(&ws[(2u * k) * SLOTS], -v);
        atomicAdd(&ws[(2u * k + 1u) * SLOTS], v);
    }
}

// Monte-Carlo LSE kernel: block = (row b) x (chunk of NPAIR antithetic pairs).
// Column mapping per lane-group g = k*512+tid (k in {0,1}):
//   h.x -> cols 4g,4g+1 ; h.y -> 4g+2,4g+3 ; h.z -> 4g+4096,+1 ; h.w -> 4g+4098,+1
__global__ __launch_bounds__(THREADS) void mc_kernel(
    const float* __restrict__ logit, const float* __restrict__ logit_var,
    const float* __restrict__ gtable, float* __restrict__ ws) {
    __shared__ __align__(16) float tbl[TBL];
    __shared__ float red[NWAVE][TCHUNK];

    const int tid = threadIdx.x;
    const unsigned b = blockIdx.x;
    const float sl2 = __builtin_amdgcn_sqrtf(logit_var[b]) * LOG2E;

    {   // stage quantile table pre-scaled by sigma*log2e
        const float4* ts = (const float4*)gtable;
        float4* td = (float4*)tbl;
#pragma unroll
        for (int i = 0; i < TBL / 4 / THREADS; ++i) {
            float4 v = ts[i * THREADS + tid];
            v.x *= sl2; v.y *= sl2; v.z *= sl2; v.w *= sl2;
            td[i * THREADS + tid] = v;
        }
    }

    const float4* z4 = (const float4*)(logit + (size_t)b * C);
    float4 zA0 = z4[tid];
    float4 zA1 = z4[tid + 512];
    float4 zB0 = z4[tid + 1024];
    float4 zB1 = z4[tid + 1536];
#define SC4(v) { v.x *= LOG2E; v.y *= LOG2E; v.z *= LOG2E; v.w *= LOG2E; }
    SC4(zA0) SC4(zA1) SC4(zB0) SC4(zB1)
#undef SC4
    __syncthreads();

    const unsigned tbase = blockIdx.y * TCHUNK;
    const unsigned kbase = blockIdx.y * NPAIR;
    const int wid = tid >> 6;
    const unsigned slot = b & (SLOTS - 1);

    for (int pp = 0; pp < NPAIR; ++pp) {
        const unsigned k = kbase + (unsigned)pp;
        const uint4 h0 = pcg4d(b, (unsigned)tid, k, SALT);
        const uint4 h1 = pcg4d(b, (unsigned)tid + 512u, k, SALT);
        v2f acc; acc.x = 0.0f; acc.y = 0.0f;
        mc_group_tbl(h0, zA0, zB0, tbl, acc);
        mc_group_tbl(h1, zA1, zB1, tbl, acc);
#pragma unroll
        for (int off = 32; off; off >>= 1) {
            acc.x += __shfl_down(acc.x, off, 64);
            acc.y += __shfl_down(acc.y, off, 64);
        }
        if ((tid & 63) == 0) {
            red[wid][2 * pp] = acc.x;       // t = tbase + 2pp   (+eps)
            red[wid][2 * pp + 1] = acc.y;   // t = tbase + 2pp+1 (-eps)
        }
    }
    __syncthreads();
    if (tid < TCHUNK) {
        float a = 0.0f;
#pragma unroll
        for (int w = 0; w < NWAVE; ++w) a += red[w][tid];
        atomicAdd(&ws[(tbase + (unsigned)tid) * SLOTS + slot],
                  __builtin_amdgcn_logf(a) * LN2);   // ln = log2 * ln2
    }
}

__global__ __launch_bounds__(64) void finalize_kernel(
    const float* __restrict__ ws, float* __restrict__ out) {
    const int lane = threadIdx.x;
    const float invB = 1.0f / (float)B;
    const float u = ws[TS] * invB;     // undistorted_loss
    const float szy = ws[TS + 2];      // sum of z_y over rows
    float g = 0.0f, v = 0.0f;
    for (int t = lane; t < T; t += 64) {
        float sumt = 0.0f;
#pragma unroll
        for (int s = 0; s < SLOTS; ++s) sumt += ws[t * SLOTS + s];
        const float dist = (sumt - szy) * invB;
        g += dist;
        const float df = u - dist;
        v -= (df > 0.0f) ? df : expm1f(df);   // -elu(diff)
    }
#pragma unroll
    for (int off = 32; off; off >>= 1) {
        g += __shfl_down(g, off, 64);
        v += __shfl_down(v, off, 64);
    }
    if (lane == 0) {
        out[0] = g / (float)T;        // gce_loss
        out[1] = v / (float)T;        // variance_loss
        out[2] = u;                   // undistorted_loss
        out[3] = ws[TS + 1] * invB;   // variance_depressor
    }
}

extern "C" void kernel_launch(void* const* d_in, const int* in_sizes, int n_in,
                              void* d_out, int out_size, void* d_ws, size_t ws_size,
                              hipStream_t stream) {
    const float* logit_var = (const float*)d_in[0];
    const float* logit     = (const float*)d_in[1];
    const int*   truth     = (const int*)d_in[2];
    float* out = (float*)d_out;
    float* ws  = (float*)d_ws;
    float* gtable = ws + TBLOFF;

    hipLaunchKernelGGL(zero_ws_kernel, dim3((TS + 3 + 255) / 256), dim3(256), 0, stream, ws);
    hipLaunchKernelGGL(table_kernel, dim3(TBL / 256), dim3(256), 0, stream, gtable);
    hipLaunchKernelGGL(rowstats_kernel, dim3(B), dim3(256), 0, stream,
                       logit, logit_var, truth, ws);
    hipLaunchKernelGGL(epsy_kernel, dim3(T / 2), dim3(256), 0, stream,
                       logit_var, truth, gtable, ws);
    hipLaunchKernelGGL(mc_kernel, dim3(B, T / TCHUNK), dim3(THREADS), 0, stream,
                       logit, logit_var, gtable, ws);
    hipLaunchKernelGGL(finalize_kernel, dim3(1), dim3(64), 0, stream, ws, out);
}